// Round 1
// baseline (135.328 us; speedup 1.0000x reference)
//
#include <hip/hip_runtime.h>

// GNNDiscriminator: fully-fused single kernel, v2.
// v1 (117.5-119.4 us harness) used ONE wave per graph -> 4096 waves total,
// a structural cap of 4 waves/SIMD: every fence/DS-latency in the per-wave
// chain is exposed. v2 splits each graph across TWO waves (128-thread block,
// one graph per block, grid=4096 -> 8192 waves -> 8/SIMD target), halving
// the per-wave critical path and doubling latency-hiding TLP.
//
// Work split per 128-thread block (graph g):
//   lane t: owns row r=t>>2, feature quarter q=t&3 (float4 of x)
//           owns 2 random edges e = g*256 + 128k + t
//           q==3 lanes additionally own row r's self-loop edge
//   wave 0 computes u_src/u_dst projection; wave 1 computes we projection
//   (projection redundancy per graph is the SAME as v1, not doubled)
//
// Identities (unchanged from v1):
//   a_src[v] = x[v].u_src, u_src = W_lin@att_src ; a_dst likewise
//   a_edge[e] = eattr[e].we, we = W_edge@att_edge
//   softmax without max-shift (|alpha|<9 by weight scaling; fp32-safe)
//   gf = ((r^T x) @ W_lin)/V + b_gat,  r[s] = sum of attn weights leaving s

#define BB   4096
#define VV   32
#define FF   16
#define NBB  8
#define CC   128
#define EPER 256
constexpr int NTOT  = BB * VV;
constexpr int ERAND = BB * EPER;
constexpr int ETOT  = ERAND + NTOT;
constexpr float SLOPE = 0.2f;

__launch_bounds__(128, 8)   // cap VGPR at 64 -> 16 blocks/CU = 32 waves/CU
__global__ void gnn_all(const float* __restrict__ x,
                        const int*   __restrict__ eidx,
                        const float* __restrict__ eattr,
                        const float* __restrict__ W_lin,
                        const float* __restrict__ att_src,
                        const float* __restrict__ att_dst,
                        const float* __restrict__ att_edge,
                        const float* __restrict__ W_edge,
                        const float* __restrict__ b_gat,
                        const float* __restrict__ W_out,
                        const float* __restrict__ b_out,
                        float* __restrict__ out,
                        float* __restrict__ gf_out)
{
  const int t    = threadIdx.x;        // 0..127
  const int lane = t & 63;
  const int wave = t >> 6;             // 0/1 (wave-uniform)
  const int g    = blockIdx.x;
  const int r    = t >> 2;             // owned node row 0..31
  const int q    = t & 3;              // feature quarter 0..3

  __shared__ float2 s_a[VV];                       // {a_src, a_dst}
  __shared__ float  s_den[VV];
  __shared__ float  s_r[VV];
  __shared__ float2 s_uv[FF];                      // {u_src[f], u_dst[f]}
  __shared__ __align__(16) float s_we[NBB];
  __shared__ __align__(16) float s_yp[2][FF];      // per-wave partial y
  __shared__ float  s_op[2];

  // ---- global loads, all issued up front ----
  const float4 xq = *(const float4*)(x + (size_t)(g * VV + r) * FF + q * 4);

  int es[2], ed[2];
  float4 ea0[2], ea1[2];
  #pragma unroll
  for (int k = 0; k < 2; ++k) {
    const int e = g * EPER + 128 * k + t;
    es[k] = eidx[e] - g * VV;
    ed[k] = eidx[ETOT + e] - g * VV;
    const float4* ap = (const float4*)(eattr + (size_t)e * NBB);
    ea0[k] = ap[0]; ea1[k] = ap[1];
  }
  // self-loop edge for row r: one lane per row quad
  const bool selfl = (q == 3);
  float4 la0 = {0,0,0,0}, la1 = {0,0,0,0};
  if (selfl) {
    const float4* lp = (const float4*)(eattr + (size_t)(ERAND + g * VV + r) * NBB);
    la0 = lp[0]; la1 = lp[1];
  }

  // ---- projections, split across the two waves (L1-hot weights) ----
  if (wave == 0) {
    // u_src/u_dst: f = lane&15, col-chunk = lane>>4 (32 cols each)
    const int fu = lane & 15, c4 = lane >> 4;
    const float4* wr = (const float4*)(W_lin + fu * CC + c4 * 32);
    const float4* as = (const float4*)(att_src + c4 * 32);
    const float4* ad = (const float4*)(att_dst + c4 * 32);
    float us = 0.f, ud = 0.f;
    #pragma unroll
    for (int j = 0; j < 8; ++j) {
      const float4 w = wr[j], a = as[j], d = ad[j];
      us += w.x*a.x + w.y*a.y + w.z*a.z + w.w*a.w;
      ud += w.x*d.x + w.y*d.y + w.z*d.z + w.w*d.w;
    }
    us += __shfl_xor(us, 16); us += __shfl_xor(us, 32);
    ud += __shfl_xor(ud, 16); ud += __shfl_xor(ud, 32);
    if (lane < FF) s_uv[lane] = make_float2(us, ud);
    if (lane < VV) { s_den[lane] = 0.f; s_r[lane] = 0.f; }
  } else {
    // we[8]: f = lane&7, col-chunk = lane>>3 (16 cols each)
    const int f8 = lane & 7, c16 = lane >> 3;
    const float4* wr = (const float4*)(W_edge + f8 * CC + c16 * 16);
    const float4* ae = (const float4*)(att_edge + c16 * 16);
    float pe = 0.f;
    #pragma unroll
    for (int j = 0; j < 4; ++j) {
      const float4 w = wr[j], a = ae[j];
      pe += w.x*a.x + w.y*a.y + w.z*a.z + w.w*a.w;
    }
    pe += __shfl_xor(pe, 8); pe += __shfl_xor(pe, 16); pe += __shfl_xor(pe, 32);
    if (lane < NBB) s_we[lane] = pe;
  }
  __syncthreads();   // B1: s_uv, s_we, zeroed s_den/s_r visible

  // ---- phase A: a_src/a_dst per row (quarter-dot, reduce over quad) ----
  float a0, a1;
  {
    const float xr[4] = {xq.x, xq.y, xq.z, xq.w};
    a0 = 0.f; a1 = 0.f;
    #pragma unroll
    for (int j = 0; j < 4; ++j) {
      const float2 u = s_uv[q * 4 + j];    // 4 addrs/instr: conflict-free
      a0 += xr[j] * u.x; a1 += xr[j] * u.y;
    }
  }
  a0 += __shfl_xor(a0, 1); a0 += __shfl_xor(a0, 2);
  a1 += __shfl_xor(a1, 1); a1 += __shfl_xor(a1, 2);
  if (q == 0) s_a[r] = make_float2(a0, a1);
  __syncthreads();   // B2

  // ---- phase B: ex = exp(leaky(alpha)), accumulate denom per dst ----
  const float4 w03 = *(const float4*)&s_we[0];
  const float4 w47 = *(const float4*)&s_we[4];
  float ex[2], exl = 0.f;
  #pragma unroll
  for (int k = 0; k < 2; ++k) {
    const float2 A = s_a[es[k]];
    const float2 D = s_a[ed[k]];
    const float aed = ea0[k].x*w03.x + ea0[k].y*w03.y + ea0[k].z*w03.z + ea0[k].w*w03.w
                    + ea1[k].x*w47.x + ea1[k].y*w47.y + ea1[k].z*w47.z + ea1[k].w*w47.w;
    const float a  = A.x + D.y + aed;
    const float al = a > 0.f ? a : SLOPE * a;
    ex[k] = __expf(al);
    atomicAdd(&s_den[ed[k]], ex[k]);
  }
  if (selfl) {
    const float2 S = s_a[r];
    const float aed = la0.x*w03.x + la0.y*w03.y + la0.z*w03.z + la0.w*w03.w
                    + la1.x*w47.x + la1.y*w47.y + la1.z*w47.z + la1.w*w47.w;
    const float a  = S.x + S.y + aed;
    const float al = a > 0.f ? a : SLOPE * a;
    exl = __expf(al);
    atomicAdd(&s_den[r], exl);
  }
  __syncthreads();   // B3

  // ---- phase C: r[src] += ex * rcp(denom[dst]) ----
  #pragma unroll
  for (int k = 0; k < 2; ++k)
    atomicAdd(&s_r[es[k]], ex[k] * __builtin_amdgcn_rcpf(s_den[ed[k]]));
  if (selfl)
    atomicAdd(&s_r[r], exl * __builtin_amdgcn_rcpf(s_den[r]));
  __syncthreads();   // B4

  // ---- phase D: y = r^T x (butterfly over rows; no LDS transpose) ----
  {
    const float rl = s_r[r];               // 4-lane broadcast: free
    float v0 = xq.x * rl, v1 = xq.y * rl, v2 = xq.z * rl, v3 = xq.w * rl;
    #pragma unroll
    for (int m = 4; m <= 32; m <<= 1) {    // reduce over this wave's 16 rows
      v0 += __shfl_xor(v0, m); v1 += __shfl_xor(v1, m);
      v2 += __shfl_xor(v2, m); v3 += __shfl_xor(v3, m);
    }
    if (lane < 4)                          // lane==q here; holds f=q*4..q*4+3
      *(float4*)&s_yp[wave][lane * 4] = make_float4(v0, v1, v2, v3);
  }
  __syncthreads();   // B5

  // ---- gf = y @ W_lin / V + b_gat ; out = gf . W_out + b_out ----
  {
    const int c = t;                       // output channel 0..127
    const float4 p0 = ((const float4*)&s_yp[0][0])[0];
    const float4 p1 = ((const float4*)&s_yp[0][0])[1];
    const float4 p2 = ((const float4*)&s_yp[0][0])[2];
    const float4 p3 = ((const float4*)&s_yp[0][0])[3];
    const float4 r0 = ((const float4*)&s_yp[1][0])[0];
    const float4 r1 = ((const float4*)&s_yp[1][0])[1];
    const float4 r2 = ((const float4*)&s_yp[1][0])[2];
    const float4 r3 = ((const float4*)&s_yp[1][0])[3];
    const float yv[16] = {
      p0.x+r0.x, p0.y+r0.y, p0.z+r0.z, p0.w+r0.w,
      p1.x+r1.x, p1.y+r1.y, p1.z+r1.z, p1.w+r1.w,
      p2.x+r2.x, p2.y+r2.y, p2.z+r2.z, p2.w+r2.w,
      p3.x+r3.x, p3.y+r3.y, p3.z+r3.z, p3.w+r3.w };
    float gacc = 0.f;
    #pragma unroll
    for (int f = 0; f < FF; ++f)
      gacc += yv[f] * W_lin[f * CC + c];   // L1-hot, coalesced
    const float gf = b_gat[c] + gacc * (1.0f / VV);
    gf_out[(size_t)g * CC + c] = gf;

    float p = gf * W_out[c];
    #pragma unroll
    for (int m = 1; m <= 32; m <<= 1) p += __shfl_xor(p, m);
    if (lane == 0) s_op[wave] = p;
  }
  __syncthreads();   // B6
  if (t == 0) out[g] = s_op[0] + s_op[1] + b_out[0];
}

extern "C" void kernel_launch(void* const* d_in, const int* in_sizes, int n_in,
                              void* d_out, int out_size, void* d_ws, size_t ws_size,
                              hipStream_t stream) {
  const float* x        = (const float*)d_in[0];
  const int*   eidx     = (const int*)  d_in[1];
  const float* eattr    = (const float*)d_in[2];
  const float* W_lin    = (const float*)d_in[3];
  const float* att_src  = (const float*)d_in[4];
  const float* att_dst  = (const float*)d_in[5];
  const float* att_edge = (const float*)d_in[6];
  const float* W_edge   = (const float*)d_in[7];
  const float* b_gat    = (const float*)d_in[8];
  const float* W_out    = (const float*)d_in[9];
  const float* b_out    = (const float*)d_in[10];

  float* out = (float*)d_out;        // [B,1] first, then gf [B,C]
  float* gf  = out + BB;

  gnn_all<<<dim3(BB), dim3(128), 0, stream>>>(
      x, eidx, eattr, W_lin, att_src, att_dst, att_edge, W_edge,
      b_gat, W_out, b_out, out, gf);
}

// Round 3
// 126.366 us; speedup vs baseline: 1.0709x; 1.0709x over previous
//
#include <hip/hip_runtime.h>

// GNNDiscriminator: fully-fused single kernel, v3 (resubmit; R2 was an infra
// failure — "container failed twice" — not a kernel signal).
// v1 (117.5-119.4 us): one wave per graph -> only 16 waves/CU, latency-exposed.
// v2 (135 us, REGRESSION): two waves/graph but __launch_bounds__(128,8) capped
//   VGPRs at 64 -> allocator spilled ~17 dwords/thread to scratch
//   (rocprof: WRITE_SIZE 38 MB vs 2.1 MB true output, VALUBusy 0.2%).
// v3: same 2-wave/graph structure, __launch_bounds__(128,6) -> 84-VGPR budget,
//   no spill; occupancy set by actual use (~60 regs -> up to 8 waves/SIMD).
//
// Work split per 128-thread block (graph g):
//   lane t: owns row r=t>>2, feature quarter q=t&3 (float4 of x)
//           owns 2 random edges e = g*256 + 128k + t
//           q==3 lanes additionally own row r's self-loop edge
//   wave 0 computes u_src/u_dst projection; wave 1 computes we projection
//
// Identities (unchanged):
//   a_src[v] = x[v].u_src, u_src = W_lin@att_src ; a_dst likewise
//   a_edge[e] = eattr[e].we, we = W_edge@att_edge
//   softmax without max-shift (|alpha|<9 by weight scaling; fp32-safe)
//   gf = ((r^T x) @ W_lin)/V + b_gat,  r[s] = sum of attn weights leaving s

#define BB   4096
#define VV   32
#define FF   16
#define NBB  8
#define CC   128
#define EPER 256
constexpr int NTOT  = BB * VV;
constexpr int ERAND = BB * EPER;
constexpr int ETOT  = ERAND + NTOT;
constexpr float SLOPE = 0.2f;

__launch_bounds__(128, 6)   // 84-VGPR budget: fits ~60-reg live set, NO SPILL
__global__ void gnn_all(const float* __restrict__ x,
                        const int*   __restrict__ eidx,
                        const float* __restrict__ eattr,
                        const float* __restrict__ W_lin,
                        const float* __restrict__ att_src,
                        const float* __restrict__ att_dst,
                        const float* __restrict__ att_edge,
                        const float* __restrict__ W_edge,
                        const float* __restrict__ b_gat,
                        const float* __restrict__ W_out,
                        const float* __restrict__ b_out,
                        float* __restrict__ out,
                        float* __restrict__ gf_out)
{
  const int t    = threadIdx.x;        // 0..127
  const int lane = t & 63;
  const int wave = t >> 6;             // 0/1 (wave-uniform)
  const int g    = blockIdx.x;
  const int r    = t >> 2;             // owned node row 0..31
  const int q    = t & 3;              // feature quarter 0..3

  __shared__ float2 s_a[VV];                       // {a_src, a_dst}
  __shared__ float  s_den[VV];
  __shared__ float  s_r[VV];
  __shared__ float2 s_uv[FF];                      // {u_src[f], u_dst[f]}
  __shared__ __align__(16) float s_we[NBB];
  __shared__ __align__(16) float s_yp[2][FF];      // per-wave partial y
  __shared__ float  s_op[2];

  // ---- global loads, all issued up front ----
  const float4 xq = *(const float4*)(x + (size_t)(g * VV + r) * FF + q * 4);

  int es[2], ed[2];
  float4 ea0[2], ea1[2];
  #pragma unroll
  for (int k = 0; k < 2; ++k) {
    const int e = g * EPER + 128 * k + t;
    es[k] = eidx[e] - g * VV;
    ed[k] = eidx[ETOT + e] - g * VV;
    const float4* ap = (const float4*)(eattr + (size_t)e * NBB);
    ea0[k] = ap[0]; ea1[k] = ap[1];
  }
  // self-loop edge for row r: one lane per row quad
  const bool selfl = (q == 3);
  float4 la0 = {0,0,0,0}, la1 = {0,0,0,0};
  if (selfl) {
    const float4* lp = (const float4*)(eattr + (size_t)(ERAND + g * VV + r) * NBB);
    la0 = lp[0]; la1 = lp[1];
  }

  // ---- projections, split across the two waves (L1-hot weights) ----
  if (wave == 0) {
    // u_src/u_dst: f = lane&15, col-chunk = lane>>4 (32 cols each)
    const int fu = lane & 15, c4 = lane >> 4;
    const float4* wr = (const float4*)(W_lin + fu * CC + c4 * 32);
    const float4* as = (const float4*)(att_src + c4 * 32);
    const float4* ad = (const float4*)(att_dst + c4 * 32);
    float us = 0.f, ud = 0.f;
    #pragma unroll
    for (int j = 0; j < 8; ++j) {
      const float4 w = wr[j], a = as[j], d = ad[j];
      us += w.x*a.x + w.y*a.y + w.z*a.z + w.w*a.w;
      ud += w.x*d.x + w.y*d.y + w.z*d.z + w.w*d.w;
    }
    us += __shfl_xor(us, 16); us += __shfl_xor(us, 32);
    ud += __shfl_xor(ud, 16); ud += __shfl_xor(ud, 32);
    if (lane < FF) s_uv[lane] = make_float2(us, ud);
    if (lane < VV) { s_den[lane] = 0.f; s_r[lane] = 0.f; }
  } else {
    // we[8]: f = lane&7, col-chunk = lane>>3 (16 cols each)
    const int f8 = lane & 7, c16 = lane >> 3;
    const float4* wr = (const float4*)(W_edge + f8 * CC + c16 * 16);
    const float4* ae = (const float4*)(att_edge + c16 * 16);
    float pe = 0.f;
    #pragma unroll
    for (int j = 0; j < 4; ++j) {
      const float4 w = wr[j], a = ae[j];
      pe += w.x*a.x + w.y*a.y + w.z*a.z + w.w*a.w;
    }
    pe += __shfl_xor(pe, 8); pe += __shfl_xor(pe, 16); pe += __shfl_xor(pe, 32);
    if (lane < NBB) s_we[lane] = pe;
  }
  __syncthreads();   // B1: s_uv, s_we, zeroed s_den/s_r visible

  // ---- phase A: a_src/a_dst per row (quarter-dot, reduce over quad) ----
  float a0, a1;
  {
    const float xr[4] = {xq.x, xq.y, xq.z, xq.w};
    a0 = 0.f; a1 = 0.f;
    #pragma unroll
    for (int j = 0; j < 4; ++j) {
      const float2 u = s_uv[q * 4 + j];    // 4 addrs/instr: conflict-free
      a0 += xr[j] * u.x; a1 += xr[j] * u.y;
    }
  }
  a0 += __shfl_xor(a0, 1); a0 += __shfl_xor(a0, 2);
  a1 += __shfl_xor(a1, 1); a1 += __shfl_xor(a1, 2);
  if (q == 0) s_a[r] = make_float2(a0, a1);
  __syncthreads();   // B2

  // ---- phase B: ex = exp(leaky(alpha)), accumulate denom per dst ----
  const float4 w03 = *(const float4*)&s_we[0];
  const float4 w47 = *(const float4*)&s_we[4];
  float ex[2], exl = 0.f;
  #pragma unroll
  for (int k = 0; k < 2; ++k) {
    const float2 A = s_a[es[k]];
    const float2 D = s_a[ed[k]];
    const float aed = ea0[k].x*w03.x + ea0[k].y*w03.y + ea0[k].z*w03.z + ea0[k].w*w03.w
                    + ea1[k].x*w47.x + ea1[k].y*w47.y + ea1[k].z*w47.z + ea1[k].w*w47.w;
    const float a  = A.x + D.y + aed;
    const float al = a > 0.f ? a : SLOPE * a;
    ex[k] = __expf(al);
    atomicAdd(&s_den[ed[k]], ex[k]);
  }
  if (selfl) {
    const float2 S = s_a[r];
    const float aed = la0.x*w03.x + la0.y*w03.y + la0.z*w03.z + la0.w*w03.w
                    + la1.x*w47.x + la1.y*w47.y + la1.z*w47.z + la1.w*w47.w;
    const float a  = S.x + S.y + aed;
    const float al = a > 0.f ? a : SLOPE * a;
    exl = __expf(al);
    atomicAdd(&s_den[r], exl);
  }
  __syncthreads();   // B3

  // ---- phase C: r[src] += ex * rcp(denom[dst]) ----
  #pragma unroll
  for (int k = 0; k < 2; ++k)
    atomicAdd(&s_r[es[k]], ex[k] * __builtin_amdgcn_rcpf(s_den[ed[k]]));
  if (selfl)
    atomicAdd(&s_r[r], exl * __builtin_amdgcn_rcpf(s_den[r]));
  __syncthreads();   // B4

  // ---- phase D: y = r^T x (butterfly over rows; no LDS transpose) ----
  {
    const float rl = s_r[r];               // 4-lane broadcast: free
    float v0 = xq.x * rl, v1 = xq.y * rl, v2 = xq.z * rl, v3 = xq.w * rl;
    #pragma unroll
    for (int m = 4; m <= 32; m <<= 1) {    // reduce over this wave's 16 rows
      v0 += __shfl_xor(v0, m); v1 += __shfl_xor(v1, m);
      v2 += __shfl_xor(v2, m); v3 += __shfl_xor(v3, m);
    }
    if (lane < 4)                          // lane==q here; holds f=q*4..q*4+3
      *(float4*)&s_yp[wave][lane * 4] = make_float4(v0, v1, v2, v3);
  }
  __syncthreads();   // B5

  // ---- gf = y @ W_lin / V + b_gat ; out = gf . W_out + b_out ----
  {
    const int c = t;                       // output channel 0..127
    const float4 p0 = ((const float4*)&s_yp[0][0])[0];
    const float4 p1 = ((const float4*)&s_yp[0][0])[1];
    const float4 p2 = ((const float4*)&s_yp[0][0])[2];
    const float4 p3 = ((const float4*)&s_yp[0][0])[3];
    const float4 r0 = ((const float4*)&s_yp[1][0])[0];
    const float4 r1 = ((const float4*)&s_yp[1][0])[1];
    const float4 r2 = ((const float4*)&s_yp[1][0])[2];
    const float4 r3 = ((const float4*)&s_yp[1][0])[3];
    const float yv[16] = {
      p0.x+r0.x, p0.y+r0.y, p0.z+r0.z, p0.w+r0.w,
      p1.x+r1.x, p1.y+r1.y, p1.z+r1.z, p1.w+r1.w,
      p2.x+r2.x, p2.y+r2.y, p2.z+r2.z, p2.w+r2.w,
      p3.x+r3.x, p3.y+r3.y, p3.z+r3.z, p3.w+r3.w };
    float gacc = 0.f;
    #pragma unroll
    for (int f = 0; f < FF; ++f)
      gacc += yv[f] * W_lin[f * CC + c];   // L1-hot, coalesced
    const float gfv = b_gat[c] + gacc * (1.0f / VV);
    gf_out[(size_t)g * CC + c] = gfv;

    float p = gfv * W_out[c];
    #pragma unroll
    for (int m = 1; m <= 32; m <<= 1) p += __shfl_xor(p, m);
    if (lane == 0) s_op[wave] = p;
  }
  __syncthreads();   // B6
  if (t == 0) out[g] = s_op[0] + s_op[1] + b_out[0];
}

extern "C" void kernel_launch(void* const* d_in, const int* in_sizes, int n_in,
                              void* d_out, int out_size, void* d_ws, size_t ws_size,
                              hipStream_t stream) {
  const float* x        = (const float*)d_in[0];
  const int*   eidx     = (const int*)  d_in[1];
  const float* eattr    = (const float*)d_in[2];
  const float* W_lin    = (const float*)d_in[3];
  const float* att_src  = (const float*)d_in[4];
  const float* att_dst  = (const float*)d_in[5];
  const float* att_edge = (const float*)d_in[6];
  const float* W_edge   = (const float*)d_in[7];
  const float* b_gat    = (const float*)d_in[8];
  const float* W_out    = (const float*)d_in[9];
  const float* b_out    = (const float*)d_in[10];

  float* out = (float*)d_out;        // [B,1] first, then gf [B,C]
  float* gf  = out + BB;

  gnn_all<<<dim3(BB), dim3(128), 0, stream>>>(
      x, eidx, eattr, W_lin, att_src, att_dst, att_edge, W_edge,
      b_gat, W_out, b_out, out, gf);
}

// Round 4
// 121.364 us; speedup vs baseline: 1.1151x; 1.0412x over previous
//
#include <hip/hip_runtime.h>

// GNNDiscriminator: fully-fused single kernel. One WAVE per graph (4/block),
// zero __syncthreads, zero cross-wave traffic. Each wave redundantly computes
// the tiny projections u_src/u_dst/we (L1-hot weights) instead of a separate
// serial precompute kernel + global ws round-trip.
//
// v4 = REVERT to v1 (proven 117.5-119.4 us harness).
// Session journal:
//   v2 (135 us): 2 waves/graph + __launch_bounds__(128,8) -> 64-VGPR cap ->
//       ~17 dw/thread scratch spill (WRITE_SIZE 38 MB vs 2.1 MB true output).
//   v3 (126 us): spill fixed (kernel <42 us) but still -7 us vs v1: the six
//       __syncthreads COUPLE the two waves (one wave's HBM stall parks its
//       partner at the barrier) and 4x block count adds dispatch overhead.
//   Lesson: v1's zero-sync independent-wave design is the right structure;
//   its kernel time (~12 us) is already near the ~9.5 us traffic floor
//   (58 MB @ 6.3 TB/s), and dur_us is dominated by the harness's two 256 MiB
//   poison fills (~84 us at 76-82% HBM peak, themselves at roofline).
//
// Identities:
//   a_src[v] = x[v].u_src, u_src = W_lin@att_src ; a_dst likewise
//   a_edge[e] = eattr[e].we, we = W_edge@att_edge
//   softmax without max-shift (|alpha|<9 by weight scaling; fp32-safe)
//   gf = ((r^T x) @ W_lin)/V + b_gat,  r[s] = sum of attn weights leaving s
//
// Intra-wave LDS ordering: DS pipe is in-order per wave; __threadfence_block
// (lgkmcnt/vmcnt drain) between phases pins compiler ordering.

#define BB   4096
#define VV   32
#define FF   16
#define NBB  8
#define CC   128
#define EPER 256
constexpr int NTOT  = BB * VV;
constexpr int ERAND = BB * EPER;
constexpr int ETOT  = ERAND + NTOT;
constexpr float SLOPE = 0.2f;

__launch_bounds__(256, 4)
__global__ void gnn_all(const float* __restrict__ x,
                        const int*   __restrict__ eidx,
                        const float* __restrict__ eattr,
                        const float* __restrict__ W_lin,
                        const float* __restrict__ att_src,
                        const float* __restrict__ att_dst,
                        const float* __restrict__ att_edge,
                        const float* __restrict__ W_edge,
                        const float* __restrict__ b_gat,
                        const float* __restrict__ W_out,
                        const float* __restrict__ b_out,
                        float* __restrict__ out,
                        float* __restrict__ gf_out)
{
  const int t    = threadIdx.x;
  const int lane = t & 63;
  const int wave = __builtin_amdgcn_readfirstlane(t) >> 6;   // uniform
  const int g    = blockIdx.x * 4 + wave;
  const int half = lane >> 5;          // 0/1: feature half of the owned row
  const int v    = lane & 31;          // owned node

  __shared__ float2 s_a[4][VV];                    // {a_src, a_dst}
  __shared__ float  s_den[4][VV];
  __shared__ float  s_r[4][VV];
  __shared__ float2 s_uv[4][FF];                   // {u_src[f], u_dst[f]}
  __shared__ __align__(16) float s_we[4][NBB];
  __shared__ float  s_xt[4][FF * 33];              // transposed r-scaled x
  __shared__ __align__(16) float s_y[4][FF];

  // ---- global loads, all issued up front ----
  // x row v, split: this lane holds features half*8 .. half*8+7
  float4 xa, xb;
  {
    const float* xp = x + (size_t)(g * VV + v) * FF + half * 8;
    xa = ((const float4*)xp)[0]; xb = ((const float4*)xp)[1];
  }
  // 4 edges per lane, lane-interleaved (fully coalesced)
  int es[4], ed[4];
  float4 ea0[4], ea1[4];
  #pragma unroll
  for (int k = 0; k < 4; ++k) {
    const int e = g * EPER + 64 * k + lane;
    es[k] = eidx[e] - g * VV;
    ed[k] = eidx[ETOT + e] - g * VV;
    const float4* ap = (const float4*)(eattr + (size_t)e * NBB);
    ea0[k] = ap[0]; ea1[k] = ap[1];
  }
  // self-loop edge for node v: upper half-wave
  float4 la0 = {0,0,0,0}, la1 = {0,0,0,0};
  if (half) {
    const float4* lp = (const float4*)(eattr + (size_t)(ERAND + g * VV + v) * NBB);
    la0 = lp[0]; la1 = lp[1];
  }

  // ---- in-wave projections: u_src/u_dst (all 64 lanes: f=lane&15, q=lane>>4) ----
  {
    const int fu = lane & 15, q = lane >> 4;
    const float4* wr = (const float4*)(W_lin + fu * CC + q * 32);
    const float4* as = (const float4*)(att_src + q * 32);
    const float4* ad = (const float4*)(att_dst + q * 32);
    float us = 0.f, ud = 0.f;
    #pragma unroll
    for (int j = 0; j < 8; ++j) {
      const float4 w = wr[j], a = as[j], d = ad[j];
      us += w.x*a.x + w.y*a.y + w.z*a.z + w.w*a.w;
      ud += w.x*d.x + w.y*d.y + w.z*d.z + w.w*d.w;
    }
    us += __shfl_xor(us, 16); us += __shfl_xor(us, 32);
    ud += __shfl_xor(ud, 16); ud += __shfl_xor(ud, 32);
    if (lane < FF) s_uv[wave][lane] = make_float2(us, ud);
  }
  // we[8]: lower half-wave (f=lane&7, oct=lane>>3)
  if (!half) {
    const int f8 = v & 7, oct = v >> 3;
    const float4* wr = (const float4*)(W_edge + f8 * CC + oct * 32);
    const float4* ae = (const float4*)(att_edge + oct * 32);
    float pe = 0.f;
    #pragma unroll
    for (int j = 0; j < 8; ++j) {
      const float4 w = wr[j], a = ae[j];
      pe += w.x*a.x + w.y*a.y + w.z*a.z + w.w*a.w;
    }
    pe += __shfl_xor(pe, 8); pe += __shfl_xor(pe, 16);
    if (v < NBB) s_we[wave][v] = pe;
  }

  // ---- a_src/a_dst: half-row dot with u (LDS-broadcast), combine halves ----
  float a0 = 0.f, a1 = 0.f;
  {
    const float xr[8] = {xa.x, xa.y, xa.z, xa.w, xb.x, xb.y, xb.z, xb.w};
    #pragma unroll
    for (int j = 0; j < 8; ++j) {
      const float2 u = s_uv[wave][half * 8 + j];   // 2 addrs/instr: conflict-free
      a0 += xr[j] * u.x; a1 += xr[j] * u.y;
    }
  }
  a0 += __shfl_xor(a0, 32); a1 += __shfl_xor(a1, 32);
  if (!half) {
    s_a[wave][v] = make_float2(a0, a1);
    s_den[wave][v] = 0.f; s_r[wave][v] = 0.f;
  }
  __threadfence_block();

  // ---- phase B: ex = exp(leaky(alpha)), accumulate denom per dst ----
  const float4 w03 = *(const float4*)&s_we[wave][0];
  const float4 w47 = *(const float4*)&s_we[wave][4];
  float ex[5];
  #pragma unroll
  for (int k = 0; k < 4; ++k) {
    const float2 A = s_a[wave][es[k]];
    const float2 D = s_a[wave][ed[k]];
    const float aed = ea0[k].x*w03.x + ea0[k].y*w03.y + ea0[k].z*w03.z + ea0[k].w*w03.w
                    + ea1[k].x*w47.x + ea1[k].y*w47.y + ea1[k].z*w47.z + ea1[k].w*w47.w;
    const float a  = A.x + D.y + aed;
    const float al = a > 0.f ? a : SLOPE * a;
    ex[k] = __expf(al);
    atomicAdd(&s_den[wave][ed[k]], ex[k]);
  }
  ex[4] = 0.f;
  if (half) {
    const float2 S = s_a[wave][v];
    const float aed = la0.x*w03.x + la0.y*w03.y + la0.z*w03.z + la0.w*w03.w
                    + la1.x*w47.x + la1.y*w47.y + la1.z*w47.z + la1.w*w47.w;
    const float a  = S.x + S.y + aed;
    const float al = a > 0.f ? a : SLOPE * a;
    ex[4] = __expf(al);
    atomicAdd(&s_den[wave][v], ex[4]);
  }
  __threadfence_block();

  // ---- phase C: r[src] += ex * rcp(denom[dst]) ----
  #pragma unroll
  for (int k = 0; k < 4; ++k)
    atomicAdd(&s_r[wave][es[k]], ex[k] * __builtin_amdgcn_rcpf(s_den[wave][ed[k]]));
  if (half)
    atomicAdd(&s_r[wave][v], ex[4] * __builtin_amdgcn_rcpf(s_den[wave][v]));
  __threadfence_block();

  // ---- phase D: y = r^T x / V via transposed scaled rows ----
  {
    const float rl = s_r[wave][v];                 // 2-way broadcast: free
    const float xr[8] = {xa.x, xa.y, xa.z, xa.w, xb.x, xb.y, xb.z, xb.w};
    #pragma unroll
    for (int j = 0; j < 8; ++j)
      s_xt[wave][(half * 8 + j) * 33 + v] = xr[j] * rl;
  }
  __threadfence_block();
  {
    const int fy = lane & 15, part = lane >> 4;
    float yp = 0.f;
    #pragma unroll
    for (int j = 0; j < 8; ++j) yp += s_xt[wave][fy * 33 + part * 8 + j];
    yp += __shfl_xor(yp, 16); yp += __shfl_xor(yp, 32);
    if (lane < FF) s_y[wave][lane] = yp * (1.0f / VV);
  }
  __threadfence_block();

  // ---- gf = y @ W_lin + b_gat ; out = gf . W_out + b_out ----
  const float4 y03 = *(const float4*)&s_y[wave][0];
  const float4 y47 = *(const float4*)&s_y[wave][4];
  const float4 y8b = *(const float4*)&s_y[wave][8];
  const float4 ycf = *(const float4*)&s_y[wave][12];
  const float yv[16] = {y03.x,y03.y,y03.z,y03.w, y47.x,y47.y,y47.z,y47.w,
                        y8b.x,y8b.y,y8b.z,y8b.w, ycf.x,ycf.y,ycf.z,ycf.w};
  const float2 bg = ((const float2*)b_gat)[lane];
  float gx = bg.x, gy = bg.y;
  const float2* W2 = (const float2*)W_lin;
  #pragma unroll
  for (int f = 0; f < FF; ++f) {
    const float2 w = W2[f * 64 + lane];            // L1-hot after first wave
    gx += yv[f] * w.x; gy += yv[f] * w.y;
  }
  ((float2*)(gf_out + (size_t)g * CC))[lane] = make_float2(gx, gy);

  const float2 wo = ((const float2*)W_out)[lane];
  float p = gx * wo.x + gy * wo.y;
  #pragma unroll
  for (int m = 1; m <= 32; m <<= 1) p += __shfl_xor(p, m);
  if (lane == 0) out[g] = p + b_out[0];
}

extern "C" void kernel_launch(void* const* d_in, const int* in_sizes, int n_in,
                              void* d_out, int out_size, void* d_ws, size_t ws_size,
                              hipStream_t stream) {
  const float* x        = (const float*)d_in[0];
  const int*   eidx     = (const int*)  d_in[1];
  const float* eattr    = (const float*)d_in[2];
  const float* W_lin    = (const float*)d_in[3];
  const float* att_src  = (const float*)d_in[4];
  const float* att_dst  = (const float*)d_in[5];
  const float* att_edge = (const float*)d_in[6];
  const float* W_edge   = (const float*)d_in[7];
  const float* b_gat    = (const float*)d_in[8];
  const float* W_out    = (const float*)d_in[9];
  const float* b_out    = (const float*)d_in[10];

  float* out = (float*)d_out;        // [B,1] first, then gf [B,C]
  float* gf  = out + BB;

  gnn_all<<<dim3(BB / 4), dim3(256), 0, stream>>>(
      x, eidx, eattr, W_lin, att_src, att_dst, att_edge, W_edge,
      b_gat, W_out, b_out, out, gf);
}